// Round 9
// baseline (102.713 us; speedup 1.0000x reference)
//
#include <hip/hip_runtime.h>
#include <math.h>

#define BB 64
#define TT 2048
#define HIDD 256
#define FASTN 64
#define SLOWN 256
#define VOC 64
#define TLOOP (TT - 3)   // 2045 scan steps
#define NEGC -1000000000.0f
#define EPAD 257         // padded emb row stride (bank-conflict-free)
#define NEGBIG (-(1 << 20))
#define BYTEAT(U, J) ((int)(((U) >> (8 * (J))) & 0xFFu))

// ---------------------------------------------------------------------------
// Single fused kernel, 64 blocks x 512 (8 waves), overlap-scheduled:
//  P1  stage emb (padded) into LDS.
//  P2  gate/dem partial dots (all waves).
//  P3  wave0: act + rank via shfl_xor (no LDS loop)  ||  waves4-7: qLast GEMV
//      first half (j = tid-256, k in [0,128)).
//  P4  waves0-3: pack 8 tokens/thread -> rank bytes + wave prefix (CS[4])
//      ||  waves4-7: GEMV second half, write qLastS = acc + bq.
//  P5  waves0-3: scatter to zsB  ||  waves4-7: write slow_mask output.
//  P6  waves0-3: time-parallel Lindley scan pass1 (4 segments: per-segment
//      max-plus map (P,Q); f(a)=max(a+p,q), fill (x,-inf), LRU (x-1,x))
//      ||  waves4-7: score partials pp[part][v] = emb[v] . qLast[part].
//  P7  waves0-3: combine entry a, pass2 -> final a + windowed evictions e
//      (slow FIFO ring = last min(n,256) evictions).
//  P8  wave0: token counts = adjacent lane diffs; count-weighted softmax
//      regroup (exact regroup of the 320-slot softmax) -> wS.
//  P9  ctx[h] = sum_u wS[u] emb[u][h].
//  P10 logits = ctx @ Wo + bo (Wo read direct from global, coalesced).
// Slot permutation is output-invariant; token counts determine the output.
// ---------------------------------------------------------------------------
__global__ __launch_bounds__(512) void k_one(
    const int* __restrict__ seq, const float* __restrict__ emb,
    const float* __restrict__ Wg, const float* __restrict__ bg,
    const float* __restrict__ Wd, const float* __restrict__ bd,
    const float* __restrict__ Wq, const float* __restrict__ bq,
    const float* __restrict__ Wo, const float* __restrict__ bo,
    float* __restrict__ out) {
  const int b = blockIdx.x;
  const int tid = threadIdx.x;
  const int lane = tid & 63;
  const int wv = tid >> 6;

  __shared__ float embS[VOC * EPAD];                    // 65792 B
  __shared__ __align__(16) unsigned char zsB[2080];
  __shared__ float qLastS[HIDD], ctxS[HIDD];
  __shared__ float pp[4][64];
  __shared__ float gp8[8][64], dp8[8][64];
  __shared__ float wS[64];
  __shared__ int prS[64], invS[64], cntTok[64];
  __shared__ int CS[4];
  __shared__ int PsS[4][64], QsS[4][64], aEndS[4][64], eSS[4][64];

  // ---- entry: seq into regs (pack threads only) ----
  const int4* seq4 = (const int4*)(seq + b * TT);
  int4 sqa = make_int4(0, 0, 0, 0), sqb = make_int4(0, 0, 0, 0);
  if (tid < 256) { sqa = seq4[2 * tid]; sqb = seq4[2 * tid + 1]; }
  const int lastv = seq[b * TT + TT - 1];

  // ---- P1: stage emb (float4 loads, padded stores) ----
  const float4* emb4 = (const float4*)emb;
  for (int i = tid; i < VOC * 64; i += 512) {
    float4 e = emb4[i];
    float* d = &embS[(i >> 6) * EPAD + ((i & 63) << 2)];
    d[0] = e.x; d[1] = e.y; d[2] = e.z; d[3] = e.w;
  }
  __syncthreads();

  // ---- P2: gate/dem partial dots: thread = (v, kp in 0..7), 32 k each ----
  {
    const int v = tid & 63, kp = tid >> 6;
    const float* er = &embS[v * EPAD + kp * 32];
    const float* wg = &Wg[kp * 32];
    const float* wd = &Wd[kp * 32];
    float g = 0.f, d = 0.f;
#pragma unroll 8
    for (int k = 0; k < 32; ++k) { float e = er[k]; g += e * wg[k]; d += e * wd[k]; }
    gp8[kp][v] = g; dp8[kp][v] = d;
  }
  __syncthreads();

  // ---- P3: wave0 rank (shfl)  ||  waves4-7 GEMV half 1 ----
  float qacc = 0.f;
  if (tid < 64) {
    float g = bg[0], dv = bd[0];
#pragma unroll
    for (int p = 0; p < 8; ++p) { g += gp8[p][tid]; dv += dp8[p][tid]; }
    int act = (1.f / (1.f + expf(-g)) >= 0.4f) ? 1 : 0;
    int r = 0;
#pragma unroll
    for (int s = 1; s < 64; ++s) {
      float du = __shfl_xor(dv, s);
      int u = lane ^ s;
      r += (du < dv || (du == dv && u < lane)) ? 1 : 0;
    }
    invS[r] = tid;
    prS[tid] = act ? r : 0xFF;
  } else if (tid >= 256) {
    const int j = tid - 256;
    const float* eL = &embS[lastv * EPAD];
#pragma unroll 8
    for (int k = 0; k < 128; ++k) qacc += eL[k] * Wq[k * HIDD + j];
  }
  __syncthreads();

  // ---- P4: waves0-3 pack 8 tokens/thread  ||  waves4-7 GEMV half 2 ----
  int by[8], cAct = 0, incl = 0;
  if (tid < 256) {
    const int t0 = tid * 8;
    int tk[8] = {sqa.x, sqa.y, sqa.z, sqa.w, sqb.x, sqb.y, sqb.z, sqb.w};
#pragma unroll
    for (int j = 0; j < 8; ++j) {
      int r = prS[tk[j]];
      by[j] = (t0 + j < TLOOP) ? r : 0xFF;
      cAct += (by[j] != 0xFF) ? 1 : 0;
    }
    incl = cAct;
    for (int s = 1; s < 64; s <<= 1) {
      int t = __shfl_up(incl, s);
      if (lane >= s) incl += t;
    }
    if (lane == 63) CS[wv] = incl;
  } else {
    const int j = tid - 256;
    const float* eL = &embS[lastv * EPAD];
#pragma unroll 8
    for (int k = 128; k < 256; ++k) qacc += eL[k] * Wq[k * HIDD + j];
    qLastS[j] = qacc + bq[j];
  }
  __syncthreads();

  // ---- shared scan geometry ----
  const int A = CS[0] + CS[1] + CS[2] + CS[3];
  const int fsplit = A < 64 ? A : 64;
  const int nL = A - fsplit;
  const int win = nL < 256 ? nL : 256;
  const int wstart = A - win;
  const int L = (((A + 3) >> 2) + 15) & ~15;  // seg len, mult of 16

  // ---- P5: scatter  ||  slow_mask store ----
  if (tid < 256) {
    int Ow = 0;
#pragma unroll
    for (int w2 = 0; w2 < 4; ++w2) Ow += (w2 < wv) ? CS[w2] : 0;
    int pos = Ow + incl - cAct;
#pragma unroll
    for (int j = 0; j < 8; ++j)
      if (by[j] != 0xFF) zsB[pos++] = (unsigned char)by[j];
  } else {
    const int j = tid - 256;
    out[BB * VOC + b * SLOWN + j] = (j < win) ? 1.0f : 0.0f;
  }
  __syncthreads();

  // ---- P6: scan pass1 (waves0-3)  ||  score partials (waves4-7) ----
  if (tid < 256) {
    const int baseW = wv * L;
    const int endW = min(baseW + L, A);
    int P = 0, Q = NEGBIG;
    for (int g = baseW; g < endW; g += 16) {
      uint4 t4 = *(const uint4*)(zsB + g);
      unsigned dsw[4] = {t4.x, t4.y, t4.z, t4.w};
      const int gHi = min(g + 16, endW);
      if (gHi == g + 16 && gHi <= fsplit) {            // FILL
#pragma unroll
        for (int d = 0; d < 4; ++d)
#pragma unroll
          for (int j = 0; j < 4; ++j) {
            int x = (BYTEAT(dsw[d], j) <= lane) ? 1 : 0;
            P += x; Q += x;
          }
      } else if (gHi == g + 16 && g >= fsplit) {       // LRU
#pragma unroll
        for (int d = 0; d < 4; ++d)
#pragma unroll
          for (int j = 0; j < 4; ++j) {
            int x = (BYTEAT(dsw[d], j) <= lane) ? 1 : 0;
            P += x - 1;
            Q = max(Q + x - 1, x);
          }
      } else {                                         // GATED
#pragma unroll
        for (int d = 0; d < 4; ++d)
#pragma unroll
          for (int j = 0; j < 4; ++j) {
            int i = g + d * 4 + j;
            int x = (BYTEAT(dsw[d], j) <= lane) ? 1 : 0;
            bool vld = i < endW;
            bool fil = i < fsplit;
            int p = fil ? x : x - 1;
            int q = fil ? NEGBIG : x;
            int Pn = P + p;
            int Qn = max(Q + p, q);
            P = vld ? Pn : P;
            Q = vld ? Qn : Q;
          }
      }
    }
    PsS[wv][lane] = P;
    QsS[wv][lane] = Q;
  } else {
    const int v = tid & 63, part = wv - 4;
    const float* er = &embS[v * EPAD + part * 64];
    const float* qr = &qLastS[part * 64];
    float s = 0.f;
#pragma unroll 8
    for (int k = 0; k < 64; ++k) s += er[k] * qr[k];
    pp[part][v] = s;
  }
  __syncthreads();

  // ---- P7: combine entry + pass2 (waves0-3) ----
  if (tid < 256) {
    int a = 0;
    for (int w2 = 0; w2 < wv; ++w2)
      a = max(a + PsS[w2][lane], QsS[w2][lane]);
    int e = 0;
    const int baseW = wv * L;
    const int endW = min(baseW + L, A);
    for (int g = baseW; g < endW; g += 16) {
      uint4 t4 = *(const uint4*)(zsB + g);
      unsigned dsw[4] = {t4.x, t4.y, t4.z, t4.w};
      const int gHi = min(g + 16, endW);
      const bool full = (gHi == g + 16);
      if (full && gHi <= fsplit) {                     // FILL
#pragma unroll
        for (int d = 0; d < 4; ++d)
#pragma unroll
          for (int j = 0; j < 4; ++j)
            a += (BYTEAT(dsw[d], j) <= lane) ? 1 : 0;
      } else if (full && g >= fsplit && gHi <= wstart) {  // MAIN
#pragma unroll
        for (int d = 0; d < 4; ++d)
#pragma unroll
          for (int j = 0; j < 4; ++j) {
            int xm1 = (BYTEAT(dsw[d], j) <= lane) ? 0 : -1;
            a = max(a, 1) + xm1;
          }
      } else if (full && g >= wstart) {                // WIN
#pragma unroll
        for (int d = 0; d < 4; ++d)
#pragma unroll
          for (int j = 0; j < 4; ++j) {
            int xm1 = (BYTEAT(dsw[d], j) <= lane) ? 0 : -1;
            e += (a > 0) ? 1 : 0;
            a = max(a, 1) + xm1;
          }
      } else {                                         // GATED
#pragma unroll
        for (int d = 0; d < 4; ++d)
#pragma unroll
          for (int j = 0; j < 4; ++j) {
            int i = g + d * 4 + j;
            int x = (BYTEAT(dsw[d], j) <= lane) ? 1 : 0;
            bool vld = i < endW;
            bool fil = i < fsplit;
            bool wg = vld && (i >= wstart);
            e += (wg && a > 0) ? 1 : 0;
            int af = a + x;
            int al = max(a, 1) + (x - 1);
            int an = fil ? af : al;
            a = vld ? an : a;
          }
      }
    }
    aEndS[wv][lane] = a;
    eSS[wv][lane] = e;
  }
  __syncthreads();

  // ---- P8: wave0 counts + softmax regroup ----
  if (tid < 64) {
    int af = aEndS[3][lane];
    int et = eSS[0][lane] + eSS[1][lane] + eSS[2][lane] + eSS[3][lane];
    int ap = __shfl_up(af, 1); if (lane == 0) ap = 0;
    int ep = __shfl_up(et, 1); if (lane == 0) ep = 0;
    cntTok[invS[lane]] = (af - ap) + (et - ep);
    // same-wave LDS write->read is ordered
    float sc = pp[0][tid] + pp[1][tid] + pp[2][tid] + pp[3][tid];
    int cc = cntTok[tid];
    float m = (cc > 0) ? sc : NEGC;
    for (int off = 32; off; off >>= 1) m = fmaxf(m, __shfl_xor(m, off));
    float w = (cc > 0) ? (float)cc * expf(sc - m) : 0.f;
    float z = w;
    for (int off = 32; off; off >>= 1) z += __shfl_xor(z, off);
    z += (float)(FASTN + SLOWN - (fsplit + win)) * expf(NEGC - m);
    wS[tid] = w / z;
  }
  __syncthreads();

  // ---- P9: ctx[h] = sum_u wS[u] * emb[u][h] ----
  if (tid < 256) {
    float cacc = 0.f;
#pragma unroll 8
    for (int u = 0; u < 64; ++u) cacc += wS[u] * embS[u * EPAD + tid];
    ctxS[tid] = cacc;
  }
  __syncthreads();

  // ---- P10: logits = ctx @ Wo + bo (Wo direct from global) ----
  if (tid < 256) {
    const int o = tid & 63, part = tid >> 6;
    const float* cr = &ctxS[part * 64];
    const float* wr = &Wo[part * 64 * VOC + o];
    float s = 0.f;
#pragma unroll 8
    for (int k = 0; k < 64; ++k) s += cr[k] * wr[k * VOC];
    pp[part][o] = s;
  }
  __syncthreads();
  if (tid < 64)
    out[b * VOC + tid] = pp[0][tid] + pp[1][tid] + pp[2][tid] + pp[3][tid] + bo[tid];
}

// ---------------------------------------------------------------------------
extern "C" void kernel_launch(void* const* d_in, const int* in_sizes, int n_in,
                              void* d_out, int out_size, void* d_ws, size_t ws_size,
                              hipStream_t stream) {
  const int*   seq = (const int*)d_in[0];
  const float* emb = (const float*)d_in[1];
  const float* Wg  = (const float*)d_in[2];
  const float* bg  = (const float*)d_in[3];
  const float* Wd  = (const float*)d_in[4];
  const float* bd  = (const float*)d_in[5];
  const float* Wq  = (const float*)d_in[6];
  const float* bq  = (const float*)d_in[7];
  const float* Wo  = (const float*)d_in[8];
  const float* bo  = (const float*)d_in[9];
  float* out = (float*)d_out;

  k_one<<<dim3(64), dim3(512), 0, stream>>>(seq, emb, Wg, bg, Wd, bd,
                                            Wq, bq, Wo, bo, out);
}

// Round 10
// 98.598 us; speedup vs baseline: 1.0417x; 1.0417x over previous
//
#include <hip/hip_runtime.h>
#include <math.h>

#define BB 64
#define TT 2048
#define HIDD 256
#define FASTN 64
#define SLOWN 256
#define VOC 64
#define TLOOP (TT - 3)   // 2045 scan steps
#define NEGC -1000000000.0f
#define EPAD 257         // padded emb row stride (bank-conflict-free)
#define NEGBIG (-(1 << 20))
#define BYTEAT(U, J) ((int)(((U) >> (8 * (J))) & 0xFFu))

// ---------------------------------------------------------------------------
// Single fused kernel, 64 blocks x 512 (8 waves).
//  P1  stage emb (padded) + Wo into LDS.
//  P2  gate/dem partial dots (all waves).
//  P3  wave0: act + rank via shfl_xor  ||  waves4-7: qLast GEMV k in [0,128).
//  P4  waves0-3: pack 8 tokens/thread + wave prefix  ||  waves4-7: GEMV
//      k in [128,256), qLastS = acc + bq.
//  P5  waves0-3: scatter rank bytes to zsB  ||  waves4-7: slow_mask store.
//  P6  ALL 8 waves: time-parallel Lindley scan pass1 (8 segments, prefetched
//      ds_read_b128): per-segment max-plus map (P,Q); f(a)=max(a+p,q),
//      fill (x,-inf), LRU (x-1,x); maps compose associatively.
//  P7  ALL: combine entry a; pass2 -> final a + windowed eviction counts e
//      (slow FIFO ring = last min(n,256) evictions).
//  P8  scores pp = emb[v].qLast (256 thr); P9 wave0 counts+softmax regroup;
//  P10 ctx; P11 logits from WoS.
// Slot permutation is output-invariant; token counts determine the output.
// ---------------------------------------------------------------------------
__global__ __launch_bounds__(512) void k_one(
    const int* __restrict__ seq, const float* __restrict__ emb,
    const float* __restrict__ Wg, const float* __restrict__ bg,
    const float* __restrict__ Wd, const float* __restrict__ bd,
    const float* __restrict__ Wq, const float* __restrict__ bq,
    const float* __restrict__ Wo, const float* __restrict__ bo,
    float* __restrict__ out) {
  const int b = blockIdx.x;
  const int tid = threadIdx.x;
  const int lane = tid & 63;
  const int wv = tid >> 6;

  __shared__ float embS[VOC * EPAD];                    // 65792 B
  __shared__ float WoS[HIDD * VOC];                     // 65536 B
  __shared__ __align__(16) unsigned char zsB[2304];     // stream + prefetch pad
  __shared__ float qLastS[HIDD], ctxS[HIDD];
  __shared__ float pp[4][64];
  __shared__ float gp8[8][64], dp8[8][64];
  __shared__ float wS[64];
  __shared__ int prS[64], invS[64], cntTok[64];
  __shared__ int CS[4];
  __shared__ int PsS[8][64], QsS[8][64], aEndS[8][64], eSS[8][64];

  // ---- entry: seq into regs (pack threads: 8 tokens each) ----
  const int4* seq4 = (const int4*)(seq + b * TT);
  int4 sqa = make_int4(0, 0, 0, 0), sqb = make_int4(0, 0, 0, 0);
  if (tid < 256) { sqa = seq4[2 * tid]; sqb = seq4[2 * tid + 1]; }
  const int lastv = seq[b * TT + TT - 1];

  // ---- P1: stage emb (float4 loads, padded stores) + Wo ----
  const float4* emb4 = (const float4*)emb;
  for (int i = tid; i < VOC * 64; i += 512) {
    float4 e = emb4[i];
    float* d = &embS[(i >> 6) * EPAD + ((i & 63) << 2)];
    d[0] = e.x; d[1] = e.y; d[2] = e.z; d[3] = e.w;
  }
  {
    const float4* Wo4 = (const float4*)Wo;
    float4* WoS4 = (float4*)WoS;
    for (int i = tid; i < HIDD * VOC / 4; i += 512) WoS4[i] = Wo4[i];
  }
  __syncthreads();

  // ---- P2: gate/dem partial dots: thread = (v, kp in 0..7), 32 k each ----
  {
    const int v = tid & 63, kp = tid >> 6;
    const float* er = &embS[v * EPAD + kp * 32];
    const float* wg = &Wg[kp * 32];
    const float* wd = &Wd[kp * 32];
    float g = 0.f, d = 0.f;
#pragma unroll 8
    for (int k = 0; k < 32; ++k) { float e = er[k]; g += e * wg[k]; d += e * wd[k]; }
    gp8[kp][v] = g; dp8[kp][v] = d;
  }
  __syncthreads();

  // ---- P3: wave0 rank (shfl)  ||  waves4-7 GEMV half 1 ----
  float qacc = 0.f;
  if (tid < 64) {
    float g = bg[0], dv = bd[0];
#pragma unroll
    for (int p = 0; p < 8; ++p) { g += gp8[p][tid]; dv += dp8[p][tid]; }
    int act = (1.f / (1.f + expf(-g)) >= 0.4f) ? 1 : 0;
    int r = 0;
#pragma unroll
    for (int s = 1; s < 64; ++s) {
      float du = __shfl_xor(dv, s);
      int u = lane ^ s;
      r += (du < dv || (du == dv && u < lane)) ? 1 : 0;
    }
    invS[r] = tid;
    prS[tid] = act ? r : 0xFF;
  } else if (tid >= 256) {
    const int j = tid - 256;
    const float* eL = &embS[lastv * EPAD];
#pragma unroll 8
    for (int k = 0; k < 128; ++k) qacc += eL[k] * Wq[k * HIDD + j];
  }
  __syncthreads();

  // ---- P4: waves0-3 pack 8 tokens/thread  ||  waves4-7 GEMV half 2 ----
  int by[8], cAct = 0, incl = 0;
  if (tid < 256) {
    const int t0 = tid * 8;
    int tk[8] = {sqa.x, sqa.y, sqa.z, sqa.w, sqb.x, sqb.y, sqb.z, sqb.w};
#pragma unroll
    for (int j = 0; j < 8; ++j) {
      int r = prS[tk[j]];
      by[j] = (t0 + j < TLOOP) ? r : 0xFF;
      cAct += (by[j] != 0xFF) ? 1 : 0;
    }
    incl = cAct;
    for (int s = 1; s < 64; s <<= 1) {
      int t = __shfl_up(incl, s);
      if (lane >= s) incl += t;
    }
    if (lane == 63) CS[wv] = incl;
  } else {
    const int j = tid - 256;
    const float* eL = &embS[lastv * EPAD];
#pragma unroll 8
    for (int k = 128; k < 256; ++k) qacc += eL[k] * Wq[k * HIDD + j];
    qLastS[j] = qacc + bq[j];
  }
  __syncthreads();

  // ---- shared scan geometry ----
  const int A = CS[0] + CS[1] + CS[2] + CS[3];
  const int fsplit = A < 64 ? A : 64;
  const int nL = A - fsplit;
  const int win = nL < 256 ? nL : 256;
  const int wstart = A - win;
  const int L = (((A + 7) >> 3) + 15) & ~15;  // seg len (8 segs), mult of 16

  // ---- P5: scatter  ||  slow_mask store ----
  if (tid < 256) {
    int Ow = 0;
#pragma unroll
    for (int w2 = 0; w2 < 4; ++w2) Ow += (w2 < wv) ? CS[w2] : 0;
    int pos = Ow + incl - cAct;
#pragma unroll
    for (int j = 0; j < 8; ++j)
      if (by[j] != 0xFF) zsB[pos++] = (unsigned char)by[j];
  } else {
    const int j = tid - 256;
    out[BB * VOC + b * SLOWN + j] = (j < win) ? 1.0f : 0.0f;
  }
  __syncthreads();

  const int baseW = wv * L;
  const int endW = min(baseW + L, A);

  // ---- P6: scan pass1, 8 segments, prefetched groups ----
  {
    int P = 0, Q = NEGBIG;
    uint4 cur = *(const uint4*)(zsB + baseW);
    for (int g = baseW; g < endW; g += 16) {
      uint4 nxt = *(const uint4*)(zsB + g + 16);  // pad: always in-bounds
      unsigned dsw[4] = {cur.x, cur.y, cur.z, cur.w};
      const int gHi = min(g + 16, endW);
      if (gHi == g + 16 && gHi <= fsplit) {            // FILL
#pragma unroll
        for (int d = 0; d < 4; ++d)
#pragma unroll
          for (int j = 0; j < 4; ++j) {
            int x = (BYTEAT(dsw[d], j) <= lane) ? 1 : 0;
            P += x; Q += x;
          }
      } else if (gHi == g + 16 && g >= fsplit) {       // LRU
#pragma unroll
        for (int d = 0; d < 4; ++d)
#pragma unroll
          for (int j = 0; j < 4; ++j) {
            int x = (BYTEAT(dsw[d], j) <= lane) ? 1 : 0;
            P += x - 1;
            Q = max(Q + x - 1, x);
          }
      } else {                                         // GATED
#pragma unroll
        for (int d = 0; d < 4; ++d)
#pragma unroll
          for (int j = 0; j < 4; ++j) {
            int i = g + d * 4 + j;
            int x = (BYTEAT(dsw[d], j) <= lane) ? 1 : 0;
            bool vld = i < endW;
            bool fil = i < fsplit;
            int p = fil ? x : x - 1;
            int q = fil ? NEGBIG : x;
            int Pn = P + p;
            int Qn = max(Q + p, q);
            P = vld ? Pn : P;
            Q = vld ? Qn : Q;
          }
      }
      cur = nxt;
    }
    PsS[wv][lane] = P;
    QsS[wv][lane] = Q;
  }
  __syncthreads();

  // ---- P7: combine entry + pass2 (prefetched) ----
  {
    int a = 0;
    for (int w2 = 0; w2 < wv; ++w2)
      a = max(a + PsS[w2][lane], QsS[w2][lane]);
    int e = 0;
    uint4 cur = *(const uint4*)(zsB + baseW);
    for (int g = baseW; g < endW; g += 16) {
      uint4 nxt = *(const uint4*)(zsB + g + 16);
      unsigned dsw[4] = {cur.x, cur.y, cur.z, cur.w};
      const int gHi = min(g + 16, endW);
      const bool full = (gHi == g + 16);
      if (full && gHi <= fsplit) {                     // FILL
#pragma unroll
        for (int d = 0; d < 4; ++d)
#pragma unroll
          for (int j = 0; j < 4; ++j)
            a += (BYTEAT(dsw[d], j) <= lane) ? 1 : 0;
      } else if (full && g >= fsplit && gHi <= wstart) {  // MAIN
#pragma unroll
        for (int d = 0; d < 4; ++d)
#pragma unroll
          for (int j = 0; j < 4; ++j) {
            int xm1 = (BYTEAT(dsw[d], j) <= lane) ? 0 : -1;
            a = max(a, 1) + xm1;
          }
      } else if (full && g >= wstart) {                // WIN
#pragma unroll
        for (int d = 0; d < 4; ++d)
#pragma unroll
          for (int j = 0; j < 4; ++j) {
            int xm1 = (BYTEAT(dsw[d], j) <= lane) ? 0 : -1;
            e += (a > 0) ? 1 : 0;
            a = max(a, 1) + xm1;
          }
      } else {                                         // GATED
#pragma unroll
        for (int d = 0; d < 4; ++d)
#pragma unroll
          for (int j = 0; j < 4; ++j) {
            int i = g + d * 4 + j;
            int x = (BYTEAT(dsw[d], j) <= lane) ? 1 : 0;
            bool vld = i < endW;
            bool fil = i < fsplit;
            bool wg = vld && (i >= wstart);
            e += (wg && a > 0) ? 1 : 0;
            int af = a + x;
            int al = max(a, 1) + (x - 1);
            int an = fil ? af : al;
            a = vld ? an : a;
          }
      }
      cur = nxt;
    }
    aEndS[wv][lane] = a;
    eSS[wv][lane] = e;
  }
  __syncthreads();

  // ---- P8: scores pp[part][v] = emb[v].qLast[part] ----
  if (tid < 256) {
    const int v = tid & 63, part = tid >> 6;
    const float* er = &embS[v * EPAD + part * 64];
    const float* qr = &qLastS[part * 64];
    float s = 0.f;
#pragma unroll 8
    for (int k = 0; k < 64; ++k) s += er[k] * qr[k];
    pp[part][v] = s;
  }
  __syncthreads();

  // ---- P9: wave0 counts + softmax regroup ----
  if (tid < 64) {
    int af = aEndS[7][lane];
    int et = 0;
#pragma unroll
    for (int w2 = 0; w2 < 8; ++w2) et += eSS[w2][lane];
    int ap = __shfl_up(af, 1); if (lane == 0) ap = 0;
    int ep = __shfl_up(et, 1); if (lane == 0) ep = 0;
    cntTok[invS[lane]] = (af - ap) + (et - ep);
    // same-wave LDS write->read is ordered
    float sc = pp[0][tid] + pp[1][tid] + pp[2][tid] + pp[3][tid];
    int cc = cntTok[tid];
    float m = (cc > 0) ? sc : NEGC;
    for (int off = 32; off; off >>= 1) m = fmaxf(m, __shfl_xor(m, off));
    float w = (cc > 0) ? (float)cc * expf(sc - m) : 0.f;
    float z = w;
    for (int off = 32; off; off >>= 1) z += __shfl_xor(z, off);
    z += (float)(FASTN + SLOWN - (fsplit + win)) * expf(NEGC - m);
    wS[tid] = w / z;
  }
  __syncthreads();

  // ---- P10: ctx[h] = sum_u wS[u] * emb[u][h] ----
  if (tid < 256) {
    float cacc = 0.f;
#pragma unroll 8
    for (int u = 0; u < 64; ++u) cacc += wS[u] * embS[u * EPAD + tid];
    ctxS[tid] = cacc;
  }
  __syncthreads();

  // ---- P11: logits = ctx @ Wo + bo (from WoS) ----
  if (tid < 256) {
    const int o = tid & 63, part = tid >> 6;
    const float* cr = &ctxS[part * 64];
    const float* wr = &WoS[part * 64 * VOC + o];
    float s = 0.f;
#pragma unroll 8
    for (int k = 0; k < 64; ++k) s += cr[k] * wr[k * VOC];
    pp[part][o] = s;
  }
  __syncthreads();
  if (tid < 64)
    out[b * VOC + tid] = pp[0][tid] + pp[1][tid] + pp[2][tid] + pp[3][tid] + bo[tid];
}

// ---------------------------------------------------------------------------
extern "C" void kernel_launch(void* const* d_in, const int* in_sizes, int n_in,
                              void* d_out, int out_size, void* d_ws, size_t ws_size,
                              hipStream_t stream) {
  const int*   seq = (const int*)d_in[0];
  const float* emb = (const float*)d_in[1];
  const float* Wg  = (const float*)d_in[2];
  const float* bg  = (const float*)d_in[3];
  const float* Wd  = (const float*)d_in[4];
  const float* bd  = (const float*)d_in[5];
  const float* Wq  = (const float*)d_in[6];
  const float* bq  = (const float*)d_in[7];
  const float* Wo  = (const float*)d_in[8];
  const float* bo  = (const float*)d_in[9];
  float* out = (float*)d_out;

  k_one<<<dim3(64), dim3(512), 0, stream>>>(seq, emb, Wg, bg, Wd, bd,
                                            Wq, bq, Wo, bo, out);
}

// Round 11
// 95.796 us; speedup vs baseline: 1.0722x; 1.0292x over previous
//
#include <hip/hip_runtime.h>
#include <math.h>

#define BB 64
#define TT 2048
#define HIDD 256
#define FASTN 64
#define SLOWN 256
#define VOC 64
#define TLOOP (TT - 3)   // 2045 scan steps
#define NEGC -1000000000.0f
#define EPAD 257         // padded emb row stride (bank-conflict-free)
#define NEGBIG (-(1 << 20))
#define BYTEAT(U, J) ((int)(((U) >> (8 * (J))) & 0xFFu))

// ---------------------------------------------------------------------------
// K1: 192 blocks x 512.
//  blocks 0..63  : per-batch scan. gate/dem dots (global emb), wave0 rank via
//    shfl_xor, pack 8 tok/thread -> compact byte stream, 8-segment prefetched
//    two-pass max-plus Lindley scan (f(a)=max(a+p,q); fill (x,-inf), LRU
//    (x-1,x); segment maps compose associatively). Outputs: cntA[b][token]
//    (fast+windowed-eviction counts; slow ring = last min(n,256) evictions),
//    AA[b], and the slow_mask rows of out.
//  blocks 64..191: qTok tiles. idx=bx-64, u=idx>>1, h=idx&1:
//    qTok[u][j] = emb[u] @ Wq[:,j] + bq[j], j in [128h, 128h+128).
// Slot permutation is output-invariant; token counts determine the output.
// ---------------------------------------------------------------------------
__global__ __launch_bounds__(512) void k_scan(
    const int* __restrict__ seq, const float* __restrict__ emb,
    const float* __restrict__ Wg, const float* __restrict__ bg,
    const float* __restrict__ Wd, const float* __restrict__ bd,
    const float* __restrict__ Wq, const float* __restrict__ bq,
    float* __restrict__ qTok, int* __restrict__ cntA, int* __restrict__ AA,
    float* __restrict__ out) {
  const int tid = threadIdx.x;
  const int lane = tid & 63;
  const int wv = tid >> 6;

  if (blockIdx.x >= 64) {
    // ================= qTok tile =================
    const int idx = (int)blockIdx.x - 64;
    const int u = idx >> 1, h = idx & 1;
    __shared__ float eS[HIDD];
    __shared__ float qp[4][128];
    if (tid < 256) eS[tid] = emb[u * HIDD + tid];
    __syncthreads();
    const int jl = tid & 127;
    const int j = jl + h * 128;
    const int kp = tid >> 7;  // 0..3
    const float* e = &eS[kp * 64];
    const float* w = &Wq[(kp * 64) * HIDD + j];
    float acc = 0.f;
#pragma unroll 8
    for (int k = 0; k < 64; ++k) acc += e[k] * w[k * HIDD];
    qp[kp][jl] = acc;
    __syncthreads();
    if (tid < 128)
      qTok[u * HIDD + tid + h * 128] =
          qp[0][tid] + qp[1][tid] + qp[2][tid] + qp[3][tid] + bq[tid + h * 128];
    return;
  }

  // ================= scan block =================
  const int b = blockIdx.x;
  __shared__ __align__(16) unsigned char zsB[2304];  // stream + prefetch pad
  __shared__ float gp8[8][64], dp8[8][64];
  __shared__ int prS[64], invS[64];
  __shared__ int CS[4];
  __shared__ int PsS[8][64], QsS[8][64], aEndS[8][64], eSS[8][64];

  // seq into regs (pack threads: 8 tokens each)
  const int4* seq4 = (const int4*)(seq + b * TT);
  int4 sqa = make_int4(0, 0, 0, 0), sqb = make_int4(0, 0, 0, 0);
  if (tid < 256) { sqa = seq4[2 * tid]; sqb = seq4[2 * tid + 1]; }

  // gate/dem partial dots straight from global: thread=(v, kp 0..7), 32 k
  {
    const int v = tid & 63, kp = tid >> 6;
    const float* er = &emb[v * HIDD + kp * 32];
    const float* wg = &Wg[kp * 32];
    const float* wd = &Wd[kp * 32];
    float g = 0.f, d = 0.f;
#pragma unroll 8
    for (int k = 0; k < 32; ++k) { float e = er[k]; g += e * wg[k]; d += e * wd[k]; }
    gp8[kp][v] = g; dp8[kp][v] = d;
  }
  __syncthreads();

  // wave0: act + rank via shfl_xor (ascending dem, ties by token id)
  if (tid < 64) {
    float g = bg[0], dv = bd[0];
#pragma unroll
    for (int p = 0; p < 8; ++p) { g += gp8[p][tid]; dv += dp8[p][tid]; }
    int act = (1.f / (1.f + expf(-g)) >= 0.4f) ? 1 : 0;
    int r = 0;
#pragma unroll
    for (int s = 1; s < 64; ++s) {
      float du = __shfl_xor(dv, s);
      int u2 = lane ^ s;
      r += (du < dv || (du == dv && u2 < lane)) ? 1 : 0;
    }
    invS[r] = tid;
    prS[tid] = act ? r : 0xFF;
  }
  __syncthreads();

  // pack 8 tokens/thread (waves0-3) + per-wave prefix
  int by[8], cAct = 0, incl = 0;
  if (tid < 256) {
    const int t0 = tid * 8;
    int tk[8] = {sqa.x, sqa.y, sqa.z, sqa.w, sqb.x, sqb.y, sqb.z, sqb.w};
#pragma unroll
    for (int j = 0; j < 8; ++j) {
      int r = prS[tk[j]];
      by[j] = (t0 + j < TLOOP) ? r : 0xFF;
      cAct += (by[j] != 0xFF) ? 1 : 0;
    }
    incl = cAct;
    for (int s = 1; s < 64; s <<= 1) {
      int t = __shfl_up(incl, s);
      if (lane >= s) incl += t;
    }
    if (lane == 63) CS[wv] = incl;
  }
  __syncthreads();

  // scan geometry
  const int A = CS[0] + CS[1] + CS[2] + CS[3];
  const int fsplit = A < 64 ? A : 64;
  const int nL = A - fsplit;
  const int win = nL < 256 ? nL : 256;
  const int wstart = A - win;
  const int L = (((A + 7) >> 3) + 15) & ~15;  // 8 segments, mult of 16

  // scatter (waves0-3)  ||  slow_mask store (waves4-7)
  if (tid < 256) {
    int Ow = 0;
#pragma unroll
    for (int w2 = 0; w2 < 4; ++w2) Ow += (w2 < wv) ? CS[w2] : 0;
    int pos = Ow + incl - cAct;
#pragma unroll
    for (int j = 0; j < 8; ++j)
      if (by[j] != 0xFF) zsB[pos++] = (unsigned char)by[j];
  } else {
    const int j = tid - 256;
    out[BB * VOC + b * SLOWN + j] = (j < win) ? 1.0f : 0.0f;
  }
  __syncthreads();

  const int baseW = wv * L;
  const int endW = min(baseW + L, A);

  // pass1: per-segment max-plus map (P,Q), prefetched groups
  {
    int P = 0, Q = NEGBIG;
    uint4 cur = *(const uint4*)(zsB + baseW);
    for (int g = baseW; g < endW; g += 16) {
      uint4 nxt = *(const uint4*)(zsB + g + 16);  // pad keeps it in-bounds
      unsigned dsw[4] = {cur.x, cur.y, cur.z, cur.w};
      const int gHi = min(g + 16, endW);
      if (gHi == g + 16 && gHi <= fsplit) {            // FILL
#pragma unroll
        for (int d = 0; d < 4; ++d)
#pragma unroll
          for (int j = 0; j < 4; ++j) {
            int x = (BYTEAT(dsw[d], j) <= lane) ? 1 : 0;
            P += x; Q += x;
          }
      } else if (gHi == g + 16 && g >= fsplit) {       // LRU
#pragma unroll
        for (int d = 0; d < 4; ++d)
#pragma unroll
          for (int j = 0; j < 4; ++j) {
            int x = (BYTEAT(dsw[d], j) <= lane) ? 1 : 0;
            P += x - 1;
            Q = max(Q + x - 1, x);
          }
      } else {                                         // GATED
#pragma unroll
        for (int d = 0; d < 4; ++d)
#pragma unroll
          for (int j = 0; j < 4; ++j) {
            int i = g + d * 4 + j;
            int x = (BYTEAT(dsw[d], j) <= lane) ? 1 : 0;
            bool vld = i < endW;
            bool fil = i < fsplit;
            int p = fil ? x : x - 1;
            int q = fil ? NEGBIG : x;
            int Pn = P + p;
            int Qn = max(Q + p, q);
            P = vld ? Pn : P;
            Q = vld ? Qn : Q;
          }
      }
      cur = nxt;
    }
    PsS[wv][lane] = P;
    QsS[wv][lane] = Q;
  }
  __syncthreads();

  // combine entry + pass2 (prefetched)
  {
    int a = 0;
    for (int w2 = 0; w2 < wv; ++w2)
      a = max(a + PsS[w2][lane], QsS[w2][lane]);
    int e = 0;
    uint4 cur = *(const uint4*)(zsB + baseW);
    for (int g = baseW; g < endW; g += 16) {
      uint4 nxt = *(const uint4*)(zsB + g + 16);
      unsigned dsw[4] = {cur.x, cur.y, cur.z, cur.w};
      const int gHi = min(g + 16, endW);
      const bool full = (gHi == g + 16);
      if (full && gHi <= fsplit) {                     // FILL
#pragma unroll
        for (int d = 0; d < 4; ++d)
#pragma unroll
          for (int j = 0; j < 4; ++j)
            a += (BYTEAT(dsw[d], j) <= lane) ? 1 : 0;
      } else if (full && g >= fsplit && gHi <= wstart) {  // MAIN
#pragma unroll
        for (int d = 0; d < 4; ++d)
#pragma unroll
          for (int j = 0; j < 4; ++j) {
            int xm1 = (BYTEAT(dsw[d], j) <= lane) ? 0 : -1;
            a = max(a, 1) + xm1;
          }
      } else if (full && g >= wstart) {                // WIN
#pragma unroll
        for (int d = 0; d < 4; ++d)
#pragma unroll
          for (int j = 0; j < 4; ++j) {
            int xm1 = (BYTEAT(dsw[d], j) <= lane) ? 0 : -1;
            e += (a > 0) ? 1 : 0;
            a = max(a, 1) + xm1;
          }
      } else {                                         // GATED
#pragma unroll
        for (int d = 0; d < 4; ++d)
#pragma unroll
          for (int j = 0; j < 4; ++j) {
            int i = g + d * 4 + j;
            int x = (BYTEAT(dsw[d], j) <= lane) ? 1 : 0;
            bool vld = i < endW;
            bool fil = i < fsplit;
            bool wg = vld && (i >= wstart);
            e += (wg && a > 0) ? 1 : 0;
            int af = a + x;
            int al = max(a, 1) + (x - 1);
            int an = fil ? af : al;
            a = vld ? an : a;
          }
      }
      cur = nxt;
    }
    aEndS[wv][lane] = a;
    eSS[wv][lane] = e;
  }
  __syncthreads();

  // wave0: token counts = adjacent lane diffs -> global
  if (tid < 64) {
    int af = aEndS[7][lane];
    int et = 0;
#pragma unroll
    for (int w2 = 0; w2 < 8; ++w2) et += eSS[w2][lane];
    int ap = __shfl_up(af, 1); if (lane == 0) ap = 0;
    int ep = __shfl_up(et, 1); if (lane == 0) ep = 0;
    cntA[b * VOC + invS[lane]] = (af - ap) + (et - ep);
    if (lane == 0) AA[b] = A;
  }
}

// ---------------------------------------------------------------------------
// K2: 64 blocks x 256 — epilogue. scores via qTok[lastv], count-weighted
// softmax regroup (exact regroup of the 320-slot softmax), ctx, logits.
// ---------------------------------------------------------------------------
__global__ __launch_bounds__(256) void k_read(
    const int* __restrict__ seq, const float* __restrict__ emb,
    const float* __restrict__ Wo, const float* __restrict__ bo,
    const float* __restrict__ qTok, const int* __restrict__ cntA,
    const int* __restrict__ AA, float* __restrict__ out) {
  const int b = blockIdx.x;
  const int tid = threadIdx.x;

  __shared__ float embS[VOC * EPAD];
  __shared__ float qLastS[HIDD], ctxS[HIDD];
  __shared__ float pp[4][64];
  __shared__ float wS[64];

  const int lastv = seq[b * TT + TT - 1];
  qLastS[tid] = qTok[lastv * HIDD + tid];
  const float4* emb4 = (const float4*)emb;
  for (int i = tid; i < VOC * 64; i += 256) {
    float4 e = emb4[i];
    float* d = &embS[(i >> 6) * EPAD + ((i & 63) << 2)];
    d[0] = e.x; d[1] = e.y; d[2] = e.z; d[3] = e.w;
  }
  __syncthreads();

  // scores pp[part][v] = emb[v] . qLast[part]
  {
    const int v = tid & 63, part = tid >> 6;
    const float* er = &embS[v * EPAD + part * 64];
    const float* qr = &qLastS[part * 64];
    float s = 0.f;
#pragma unroll 8
    for (int k = 0; k < 64; ++k) s += er[k] * qr[k];
    pp[part][v] = s;
  }
  __syncthreads();

  // wave0: softmax regroup over token counts
  if (tid < 64) {
    const int A = AA[b];
    const int fsplit = A < 64 ? A : 64;
    const int nL = A - fsplit;
    const int win = nL < 256 ? nL : 256;
    float sc = pp[0][tid] + pp[1][tid] + pp[2][tid] + pp[3][tid];
    int cc = cntA[b * VOC + tid];
    float m = (cc > 0) ? sc : NEGC;
    for (int off = 32; off; off >>= 1) m = fmaxf(m, __shfl_xor(m, off));
    float w = (cc > 0) ? (float)cc * expf(sc - m) : 0.f;
    float z = w;
    for (int off = 32; off; off >>= 1) z += __shfl_xor(z, off);
    z += (float)(FASTN + SLOWN - (fsplit + win)) * expf(NEGC - m);  // 0 unless empty
    wS[tid] = w / z;
  }
  __syncthreads();

  // ctx[h] = sum_u wS[u] * emb[u][h]
  {
    float cacc = 0.f;
#pragma unroll 8
    for (int u = 0; u < 64; ++u) cacc += wS[u] * embS[u * EPAD + tid];
    ctxS[tid] = cacc;
  }
  __syncthreads();

  // logits = ctx @ Wo + bo (Wo read once from global)
  {
    const int o = tid & 63, part = tid >> 6;
    const float* cr = &ctxS[part * 64];
    const float* wr = &Wo[part * 64 * VOC + o];
    float s = 0.f;
#pragma unroll 8
    for (int k = 0; k < 64; ++k) s += cr[k] * wr[k * VOC];
    pp[part][o] = s;
  }
  __syncthreads();
  if (tid < 64)
    out[b * VOC + tid] = pp[0][tid] + pp[1][tid] + pp[2][tid] + pp[3][tid] + bo[tid];
}

// ---------------------------------------------------------------------------
extern "C" void kernel_launch(void* const* d_in, const int* in_sizes, int n_in,
                              void* d_out, int out_size, void* d_ws, size_t ws_size,
                              hipStream_t stream) {
  const int*   seq = (const int*)d_in[0];
  const float* emb = (const float*)d_in[1];
  const float* Wg  = (const float*)d_in[2];
  const float* bg  = (const float*)d_in[3];
  const float* Wd  = (const float*)d_in[4];
  const float* bd  = (const float*)d_in[5];
  const float* Wq  = (const float*)d_in[6];
  const float* bq  = (const float*)d_in[7];
  const float* Wo  = (const float*)d_in[8];
  const float* bo  = (const float*)d_in[9];
  float* out = (float*)d_out;

  char* ws = (char*)d_ws;
  float* qTok = (float*)ws;                    // 64*256 floats = 65536 B
  int*   cntA = (int*)(ws + 65536);            // 64*64 ints   = 16384 B
  int*   AA   = (int*)(ws + 65536 + 16384);    // 64 ints

  k_scan<<<dim3(192), dim3(512), 0, stream>>>(seq, emb, Wg, bg, Wd, bd,
                                              Wq, bq, qTok, cntA, AA, out);
  k_read<<<dim3(64), dim3(256), 0, stream>>>(seq, emb, Wo, bo,
                                             qTok, cntA, AA, out);
}